// Round 15
// baseline (184.443 us; speedup 1.0000x reference)
//
#include <hip/hip_runtime.h>
#include <hip/hip_bf16.h>

#define B_    128
#define T_    1000
#define D_    1024
#define H_    256
#define TCROP 100
#define CHUNK 50
#define NCH   20            // T_/CHUNK
#define CSKIP 2             // TCROP/CHUNK (exact)

typedef __attribute__((ext_vector_type(8))) short bfrag8;   // 8 x bf16
typedef __attribute__((ext_vector_type(4))) float f32x4;
typedef unsigned long long ull;

__device__ __forceinline__ unsigned short f2bf(float f) {
    union { float f; unsigned int u; } v; v.f = f;
    unsigned int u = v.u;
    u += 0x7FFFu + ((u >> 16) & 1u);   // RNE
    return (unsigned short)(u >> 16);
}
__device__ __forceinline__ float bf2f(unsigned short u) {
    union { unsigned int u; float f; } v; v.u = ((unsigned int)u) << 16;
    return v.f;
}
// pack two f32 -> (bf16(hi)<<16)|bf16(lo), round-half-away: 2 adds + 1 v_perm
__device__ __forceinline__ unsigned int pack2(float lo, float hi) {
    union { float f; unsigned int u; } a, b; a.f = lo; b.f = hi;
    return __builtin_amdgcn_perm(b.u + 0x8000u, a.u + 0x8000u, 0x07060302u);
}
__device__ __forceinline__ bfrag8 cvt8(float4 f0, float4 f1) {
    union { bfrag8 v; unsigned int u[4]; } r;
    r.u[0] = pack2(f0.x, f0.y);
    r.u[1] = pack2(f0.z, f0.w);
    r.u[2] = pack2(f1.x, f1.y);
    r.u[3] = pack2(f1.z, f1.w);
    return r.v;
}

// ---------------------------------------------------------------------------
// Kernel 0: W f32 [H][D] -> bf16 (row-major)
// ---------------------------------------------------------------------------
__global__ __launch_bounds__(256) void wconv_kernel(
        const float* __restrict__ W, unsigned short* __restrict__ Wbf) {
    const int i = (blockIdx.x * 256 + threadIdx.x) * 8;
    float4 f0 = *(const float4*)(W + i);
    float4 f1 = *(const float4*)(W + i + 4);
    *(bfrag8*)(Wbf + i) = cvt8(f0, f1);
}

// ---------------------------------------------------------------------------
// Kernel 1: Wx = x(bf16) . W^T. K-loop/staging = R10 CHAMPION byte-identical.
// Epilogue: acc -> LDS C-tile (as r10), then waves 0-3 run the chunk-segment
// EMA in-LDS (kills scanA: chunk of 50 splits across <=2 blocks of 128 ->
// emit Seg[g][0] (segment starting at chunk start) / Seg[g][1] (tail after a
// block boundary); scanB composes), waves 4-7 do the coalesced Wx stores.
// ---------------------------------------------------------------------------
__global__ __launch_bounds__(512) void gemm_kernel(
        const float* __restrict__ x, const unsigned short* __restrict__ Wbf,
        const float* __restrict__ alpha,
        unsigned short* __restrict__ Wx, float* __restrict__ Seg) {
    __shared__ unsigned short smem[32768];    // 64 KB
    unsigned short* As = smem;                // [128][64] bf16 (16 KB)
    unsigned short* Bs = smem + 128 * 64;     // [256][64] bf16 (32 KB)

    const int tid  = threadIdx.x;
    const int lane = tid & 63;
    const int wave = tid >> 6;
    const int wr   = wave >> 2;          // 0..1
    const int wc   = wave & 3;           // 0..3
    const int m0   = blockIdx.x * 128;

    f32x4 acc[4][4];
#pragma unroll
    for (int m = 0; m < 4; ++m)
#pragma unroll
        for (int n = 0; n < 4; ++n) acc[m][n] = (f32x4){0.f, 0.f, 0.f, 0.f};

    const int rr  = lane & 15;
    const int kh  = lane >> 4;           // 0..3
    const int ra0 = tid >> 3;            // A-stage row (and +64)
    const int ja  = tid & 7;             // A-stage chunk
    const int sa  = (ja ^ (ra0 & 7)) * 8;

    for (int kt = 0; kt < D_; kt += 64) {
        // ---- B stage: 4x global_load_lds, 16B/lane, source pre-swizzled ----
#pragma unroll
        for (int q = 0; q < 4; ++q) {
            const int li = q * 512 + tid;        // 0..2047
            const int r  = li >> 3;
            const int j  = li & 7;
            const int jj = j ^ (r & 7);
            const unsigned short* src = Wbf + (size_t)r * D_ + kt + jj * 8;
            unsigned short* dst = &Bs[li * 8];
            __builtin_amdgcn_global_load_lds(
                (const __attribute__((address_space(1))) void*)src,
                (__attribute__((address_space(3))) void*)dst, 16, 0, 0);
        }
        // ---- A stage: reg path, f32->bf16, write-side swizzle ----
#pragma unroll
        for (int q = 0; q < 2; ++q) {
            const int r = ra0 + q * 64;
            const float* src = x + (size_t)(m0 + r) * D_ + kt + ja * 8;
            float4 f0 = *(const float4*)src;
            float4 f1 = *(const float4*)(src + 4);
            *(bfrag8*)&As[r * 64 + sa] = cvt8(f0, f1);
        }
        __syncthreads();

        // ---- fragments + MFMA ----
#pragma unroll
        for (int kk = 0; kk < 2; ++kk) {
            const int c16 = kk * 4 + kh;
            bfrag8 af[4], bfr[4];
#pragma unroll
            for (int m = 0; m < 4; ++m) {
                const int row = wr * 64 + m * 16 + rr;
                af[m] = *(const bfrag8*)&As[row * 64 + ((c16 ^ (row & 7)) * 8)];
            }
#pragma unroll
            for (int n = 0; n < 4; ++n) {
                const int row = wc * 64 + n * 16 + rr;
                bfr[n] = *(const bfrag8*)&Bs[row * 64 + ((c16 ^ (row & 7)) * 8)];
            }
#pragma unroll
            for (int m = 0; m < 4; ++m)
#pragma unroll
                for (int n = 0; n < 4; ++n)
                    acc[m][n] = __builtin_amdgcn_mfma_f32_16x16x32_bf16(
                        af[m], bfr[n], acc[m][n], 0, 0, 0);
        }
        __syncthreads();
    }

    // ---- epilogue: acc -> LDS C-tile [128][256] bf16 (col-XOR swizzle) ----
    const int cl = lane & 15, rg = lane >> 4;
#pragma unroll
    for (int m = 0; m < 4; ++m)
#pragma unroll
        for (int n = 0; n < 4; ++n)
#pragma unroll
            for (int j = 0; j < 4; ++j) {
                const int row = wr * 64 + m * 16 + rg * 4 + j;
                const int col = wc * 64 + n * 16 + cl;
                smem[row * 256 + (col ^ (((row >> 2) & 3) << 4))] =
                    f2bf(acc[m][n][j]);
            }
    __syncthreads();

    if (tid < 256) {
        // ---- waves 0-3: chunk-segment EMA over the 128 rows (zero-seeded
        //      per segment; segments delimited by chunk starts (flat%50==0)
        //      and block edges). Emits 3-4 Seg values. ----
        const int h = tid;
        const float AMIN = 0.81873075307798182f, AMAX = 0.96078943915232320f;
        const float a  = fminf(fmaxf(alpha[h], AMIN), AMAX);
        const float om = 1.0f - a;
        float ut = 0.f;
        int g = m0 / CHUNK;           // global chunk id of row m0
        int segstart = 0;
        for (int r = 0; r < 128; ++r) {
            ut = a * ut + om * bf2f(smem[r * 256 + (h ^ (((r >> 2) & 3) << 4))]);
            if (((m0 + r) % CHUNK) == (CHUNK - 1) || r == 127) {
                const int which = ((m0 + segstart) % CHUNK == 0) ? 0 : 1;
                Seg[((size_t)g * 2 + which) * H_ + h] = ut;
                ut = 0.f;
                ++g;
                segstart = r + 1;
            }
        }
    } else {
        // ---- waves 4-7: coalesced b128 Wx stores from LDS ----
        for (int li = tid - 256; li < 4096; li += 256) {
            const int r  = li >> 5;                    // 0..127
            const int cg = (li & 31) * 8;              // granule base col
            const int scg = cg ^ (((r >> 2) & 3) << 4);
            bfrag8 v = *(const bfrag8*)&smem[r * 256 + scg];
            *(bfrag8*)&Wx[(size_t)(m0 + r) * H_ + cg] = v;
        }
    }
}

// ---------------------------------------------------------------------------
// Kernel 2 (scanB): compose chunk segments -> F, then carry prefix S.
// Split point of chunk g = first multiple of 128 in [g*50, g*50+50):
//   F = a^len1 * Seg[g][0] + Seg[g][1]  (len1 = g*50+50-p) if split, else
//   F = Seg[g][0].
// ---------------------------------------------------------------------------
__global__ __launch_bounds__(256) void scanB_kernel(
        const float* __restrict__ Seg, const float* __restrict__ alpha,
        float* __restrict__ S) {
    const int b = blockIdx.x, h = threadIdx.x;
    const float AMIN = 0.81873075307798182f, AMAX = 0.96078943915232320f;
    const float a = fminf(fmaxf(alpha[h], AMIN), AMAX);
    const float aL = __powf(a, (float)CHUNK);
    float s = 0.f;
#pragma unroll
    for (int c = 0; c < NCH; ++c) {
        S[((size_t)b * NCH + c) * H_ + h] = s;
        const int g  = b * NCH + c;
        const int cs = g * CHUNK;
        const int p  = ((cs >> 7) + 1) << 7;          // next block edge
        float F = Seg[((size_t)g * 2) * H_ + h];
        if (p < cs + CHUNK) {
            const int len1 = cs + CHUNK - p;
            F = __powf(a, (float)len1) * F + Seg[((size_t)g * 2 + 1) * H_ + h];
        }
        s = aL * s + F;
    }
}

// ---------------------------------------------------------------------------
// Kernel 3 (scanC): seeded re-run + softmax accumulation (5-t batched shfl).
// ---------------------------------------------------------------------------
__global__ __launch_bounds__(64) void scanC_kernel(
        const unsigned short* __restrict__ Wx, const float* __restrict__ alpha,
        const float* __restrict__ S, float* __restrict__ P) {
    const int c = blockIdx.x + CSKIP;     // 2..19
    const int b = blockIdx.y;
    const int lane = threadIdx.x;
    const int h = lane * 4;

    const float AMIN = 0.81873075307798182f, AMAX = 0.96078943915232320f;
    float4 al = *(const float4*)(alpha + h);
    float a[4]  = {fminf(fmaxf(al.x, AMIN), AMAX), fminf(fmaxf(al.y, AMIN), AMAX),
                   fminf(fmaxf(al.z, AMIN), AMAX), fminf(fmaxf(al.w, AMIN), AMAX)};
    float om[4] = {1.f - a[0], 1.f - a[1], 1.f - a[2], 1.f - a[3]};

    float4 s0 = *(const float4*)(S + ((size_t)b * NCH + c) * H_ + h);
    float ut[4]   = {s0.x, s0.y, s0.z, s0.w};
    float acc4[4] = {0.f, 0.f, 0.f, 0.f};

    const unsigned short* base = Wx + ((size_t)b * T_ + c * CHUNK) * H_ + h;
#pragma unroll
    for (int tb = 0; tb < CHUNK; tb += 5) {
        float e[5][4], sl[5];
#pragma unroll
        for (int q = 0; q < 5; ++q) {
            ull wv = *(const ull*)(base + (size_t)(tb + q) * H_);
            ut[0] = a[0] * ut[0] + om[0] * bf2f((unsigned short)wv);
            ut[1] = a[1] * ut[1] + om[1] * bf2f((unsigned short)(wv >> 16));
            ut[2] = a[2] * ut[2] + om[2] * bf2f((unsigned short)(wv >> 32));
            ut[3] = a[3] * ut[3] + om[3] * bf2f((unsigned short)(wv >> 48));
            e[q][0] = __expf(ut[0]);   // |ut| small: overflow impossible
            e[q][1] = __expf(ut[1]);
            e[q][2] = __expf(ut[2]);
            e[q][3] = __expf(ut[3]);
            sl[q] = (e[q][0] + e[q][1]) + (e[q][2] + e[q][3]);
        }
#pragma unroll
        for (int dd = 1; dd < 64; dd <<= 1) {
            sl[0] += __shfl_xor(sl[0], dd);
            sl[1] += __shfl_xor(sl[1], dd);
            sl[2] += __shfl_xor(sl[2], dd);
            sl[3] += __shfl_xor(sl[3], dd);
            sl[4] += __shfl_xor(sl[4], dd);
        }
#pragma unroll
        for (int q = 0; q < 5; ++q) {
            const float rcp = 1.0f / sl[q];
            acc4[0] += e[q][0] * rcp;
            acc4[1] += e[q][1] * rcp;
            acc4[2] += e[q][2] * rcp;
            acc4[3] += e[q][3] * rcp;
        }
    }
    float4 o; o.x = acc4[0]; o.y = acc4[1]; o.z = acc4[2]; o.w = acc4[3];
    *(float4*)(P + ((size_t)b * NCH + c) * H_ + h) = o;
}

__global__ __launch_bounds__(256) void scanD_kernel(
        const float* __restrict__ P, float* __restrict__ out) {
    const int b = blockIdx.x, h = threadIdx.x;
    float s = 0.f;
    for (int c = CSKIP; c < NCH; ++c) s += P[((size_t)b * NCH + c) * H_ + h];
    out[(size_t)b * H_ + h] = s;
}

extern "C" void kernel_launch(void* const* d_in, const int* in_sizes, int n_in,
                              void* d_out, int out_size, void* d_ws, size_t ws_size,
                              hipStream_t stream) {
    const float* x     = (const float*)d_in[0];   // [B,T,D]
    const float* W     = (const float*)d_in[1];   // [H,D]
    const float* alpha = (const float*)d_in[2];   // [H]
    float* out = (float*)d_out;                   // [B,H]

    char* ws = (char*)d_ws;
    unsigned short* Wbf = (unsigned short*)ws;                        // 512 KB
    unsigned short* Wx  = (unsigned short*)(ws + ((size_t)1 << 20));  // 65.5 MB
    float* Seg = (float*)(ws + ((size_t)70 << 20));                   // 5.24 MB
    float* S   = (float*)(ws + ((size_t)80 << 20));                   // 2.62 MB
    float* P   = (float*)(ws + ((size_t)90 << 20));                   // 2.62 MB

    wconv_kernel<<<128, 256, 0, stream>>>(W, Wbf);
    gemm_kernel<<<(B_ * T_) / 128, 512, 0, stream>>>(x, Wbf, alpha, Wx, Seg);
    scanB_kernel<<<B_, H_, 0, stream>>>(Seg, alpha, S);
    scanC_kernel<<<dim3(NCH - CSKIP, B_), 64, 0, stream>>>(Wx, alpha, S, P);
    scanD_kernel<<<B_, 256, 0, stream>>>(P, out);
}

// Round 16
// 174.268 us; speedup vs baseline: 1.0584x; 1.0584x over previous
//
#include <hip/hip_runtime.h>
#include <hip/hip_bf16.h>

#define B_    128
#define T_    1000
#define D_    1024
#define H_    256
#define TCROP 100
#define CHUNK 50
#define NCH   20            // T_/CHUNK
#define CSKIP 2             // TCROP/CHUNK (exact)

typedef __attribute__((ext_vector_type(8))) short bfrag8;   // 8 x bf16
typedef __attribute__((ext_vector_type(4))) float f32x4;
typedef unsigned long long ull;

__device__ __forceinline__ unsigned short f2bf(float f) {
    union { float f; unsigned int u; } v; v.f = f;
    unsigned int u = v.u;
    u += 0x7FFFu + ((u >> 16) & 1u);   // RNE
    return (unsigned short)(u >> 16);
}
__device__ __forceinline__ float bf2f(unsigned short u) {
    union { unsigned int u; float f; } v; v.u = ((unsigned int)u) << 16;
    return v.f;
}
// pack two f32 -> (bf16(hi)<<16)|bf16(lo), round-half-away: 2 adds + 1 v_perm
__device__ __forceinline__ unsigned int pack2(float lo, float hi) {
    union { float f; unsigned int u; } a, b; a.f = lo; b.f = hi;
    return __builtin_amdgcn_perm(b.u + 0x8000u, a.u + 0x8000u, 0x07060302u);
}
__device__ __forceinline__ bfrag8 cvt8(float4 f0, float4 f1) {
    union { bfrag8 v; unsigned int u[4]; } r;
    r.u[0] = pack2(f0.x, f0.y);
    r.u[1] = pack2(f0.z, f0.w);
    r.u[2] = pack2(f1.x, f1.y);
    r.u[3] = pack2(f1.z, f1.w);
    return r.v;
}

// ---------------------------------------------------------------------------
// Kernel 0: W f32 [H][D] -> bf16 (row-major)
// ---------------------------------------------------------------------------
__global__ __launch_bounds__(256) void wconv_kernel(
        const float* __restrict__ W, unsigned short* __restrict__ Wbf) {
    const int i = (blockIdx.x * 256 + threadIdx.x) * 8;
    float4 f0 = *(const float4*)(W + i);
    float4 f1 = *(const float4*)(W + i + 4);
    *(bfrag8*)(Wbf + i) = cvt8(f0, f1);
}

// ---------------------------------------------------------------------------
// Kernel 1: Wx = x(bf16) . W^T. R10 CHAMPION, byte-identical (174 us).
// BM=128, BN=256(=H: A read exactly once), BK=64, 512 thr, single-buffer
// 48 KB LDS, 2 barriers/K-step, B gload_lds first, A reg+pack2 cvt,
// coalesced LDS C-tile epilogue. All pipelining/fusion/retile variants
// (r3,r5,r7,r8,r11,r13,r15) regressed: 2 blocks/CU implicit cross-block
// overlap is the winning schedule at this size.
// ---------------------------------------------------------------------------
__global__ __launch_bounds__(512) void gemm_kernel(
        const float* __restrict__ x, const unsigned short* __restrict__ Wbf,
        unsigned short* __restrict__ Wx) {
    __shared__ unsigned short smem[32768];    // 64 KB
    unsigned short* As = smem;                // [128][64] bf16 (16 KB)
    unsigned short* Bs = smem + 128 * 64;     // [256][64] bf16 (32 KB)

    const int tid  = threadIdx.x;
    const int lane = tid & 63;
    const int wave = tid >> 6;
    const int wr   = wave >> 2;          // 0..1
    const int wc   = wave & 3;           // 0..3
    const int m0   = blockIdx.x * 128;

    f32x4 acc[4][4];
#pragma unroll
    for (int m = 0; m < 4; ++m)
#pragma unroll
        for (int n = 0; n < 4; ++n) acc[m][n] = (f32x4){0.f, 0.f, 0.f, 0.f};

    const int rr  = lane & 15;
    const int kh  = lane >> 4;           // 0..3
    const int ra0 = tid >> 3;            // A-stage row (and +64)
    const int ja  = tid & 7;             // A-stage chunk
    const int sa  = (ja ^ (ra0 & 7)) * 8;

    for (int kt = 0; kt < D_; kt += 64) {
        // ---- B stage: 4x global_load_lds, 16B/lane, source pre-swizzled ----
#pragma unroll
        for (int q = 0; q < 4; ++q) {
            const int li = q * 512 + tid;        // 0..2047
            const int r  = li >> 3;
            const int j  = li & 7;
            const int jj = j ^ (r & 7);
            const unsigned short* src = Wbf + (size_t)r * D_ + kt + jj * 8;
            unsigned short* dst = &Bs[li * 8];
            __builtin_amdgcn_global_load_lds(
                (const __attribute__((address_space(1))) void*)src,
                (__attribute__((address_space(3))) void*)dst, 16, 0, 0);
        }
        // ---- A stage: reg path, f32->bf16, write-side swizzle ----
#pragma unroll
        for (int q = 0; q < 2; ++q) {
            const int r = ra0 + q * 64;
            const float* src = x + (size_t)(m0 + r) * D_ + kt + ja * 8;
            float4 f0 = *(const float4*)src;
            float4 f1 = *(const float4*)(src + 4);
            *(bfrag8*)&As[r * 64 + sa] = cvt8(f0, f1);
        }
        __syncthreads();

        // ---- fragments + MFMA ----
#pragma unroll
        for (int kk = 0; kk < 2; ++kk) {
            const int c16 = kk * 4 + kh;
            bfrag8 af[4], bfr[4];
#pragma unroll
            for (int m = 0; m < 4; ++m) {
                const int row = wr * 64 + m * 16 + rr;
                af[m] = *(const bfrag8*)&As[row * 64 + ((c16 ^ (row & 7)) * 8)];
            }
#pragma unroll
            for (int n = 0; n < 4; ++n) {
                const int row = wc * 64 + n * 16 + rr;
                bfr[n] = *(const bfrag8*)&Bs[row * 64 + ((c16 ^ (row & 7)) * 8)];
            }
#pragma unroll
            for (int m = 0; m < 4; ++m)
#pragma unroll
                for (int n = 0; n < 4; ++n)
                    acc[m][n] = __builtin_amdgcn_mfma_f32_16x16x32_bf16(
                        af[m], bfr[n], acc[m][n], 0, 0, 0);
        }
        __syncthreads();
    }

    // ---- epilogue: acc -> LDS C-tile [128][256] bf16 (col-XOR swizzle),
    //      then coalesced b128 stores ----
    const int cl = lane & 15, rg = lane >> 4;
#pragma unroll
    for (int m = 0; m < 4; ++m)
#pragma unroll
        for (int n = 0; n < 4; ++n)
#pragma unroll
            for (int j = 0; j < 4; ++j) {
                const int row = wr * 64 + m * 16 + rg * 4 + j;
                const int col = wc * 64 + n * 16 + cl;
                smem[row * 256 + (col ^ (((row >> 2) & 3) << 4))] =
                    f2bf(acc[m][n][j]);
            }
    __syncthreads();
#pragma unroll
    for (int li = tid; li < 4096; li += 512) {
        const int r  = li >> 5;                    // 0..127
        const int cg = (li & 31) * 8;              // granule base col
        const int scg = cg ^ (((r >> 2) & 3) << 4);
        bfrag8 v = *(const bfrag8*)&smem[r * 256 + scg];
        *(bfrag8*)&Wx[(size_t)(m0 + r) * H_ + cg] = v;
    }
}

// ---------------------------------------------------------------------------
// Kernel 2 (scanA): per (b,c) zero-seeded chunk-final EMA F. 10-deep unroll.
// ---------------------------------------------------------------------------
__global__ __launch_bounds__(64) void scanA_kernel(
        const unsigned short* __restrict__ Wx, const float* __restrict__ alpha,
        float* __restrict__ F) {
    const int c = blockIdx.x, b = blockIdx.y;
    const int lane = threadIdx.x;
    const int h = lane * 4;

    const float AMIN = 0.81873075307798182f, AMAX = 0.96078943915232320f;
    float4 al = *(const float4*)(alpha + h);
    float a[4]  = {fminf(fmaxf(al.x, AMIN), AMAX), fminf(fmaxf(al.y, AMIN), AMAX),
                   fminf(fmaxf(al.z, AMIN), AMAX), fminf(fmaxf(al.w, AMIN), AMAX)};
    float om[4] = {1.f - a[0], 1.f - a[1], 1.f - a[2], 1.f - a[3]};

    float ut[4] = {0.f, 0.f, 0.f, 0.f};
    const unsigned short* base = Wx + ((size_t)b * T_ + c * CHUNK) * H_ + h;
#pragma unroll 10
    for (int t = 0; t < CHUNK; ++t) {
        ull wv = *(const ull*)(base + (size_t)t * H_);
        ut[0] = a[0] * ut[0] + om[0] * bf2f((unsigned short)wv);
        ut[1] = a[1] * ut[1] + om[1] * bf2f((unsigned short)(wv >> 16));
        ut[2] = a[2] * ut[2] + om[2] * bf2f((unsigned short)(wv >> 32));
        ut[3] = a[3] * ut[3] + om[3] * bf2f((unsigned short)(wv >> 48));
    }
    float4 o; o.x = ut[0]; o.y = ut[1]; o.z = ut[2]; o.w = ut[3];
    *(float4*)(F + ((size_t)b * NCH + c) * H_ + h) = o;
}

// ---------------------------------------------------------------------------
// Kernel 3 (scanB): carry prefix S over chunks, fully unrolled.
// ---------------------------------------------------------------------------
__global__ __launch_bounds__(256) void scanB_kernel(
        const float* __restrict__ F, const float* __restrict__ alpha,
        float* __restrict__ S) {
    const int b = blockIdx.x, h = threadIdx.x;
    const float AMIN = 0.81873075307798182f, AMAX = 0.96078943915232320f;
    const float a = fminf(fmaxf(alpha[h], AMIN), AMAX);
    const float aL = powf(a, (float)CHUNK);
    float f[NCH];
#pragma unroll
    for (int c = 0; c < NCH; ++c)
        f[c] = F[((size_t)b * NCH + c) * H_ + h];
    float s = 0.f;
#pragma unroll
    for (int c = 0; c < NCH; ++c) {
        S[((size_t)b * NCH + c) * H_ + h] = s;
        s = aL * s + f[c];
    }
}

// ---------------------------------------------------------------------------
// Kernel 4 (scanC): seeded re-run + softmax accumulation (5-t batched shfl).
// ---------------------------------------------------------------------------
__global__ __launch_bounds__(64) void scanC_kernel(
        const unsigned short* __restrict__ Wx, const float* __restrict__ alpha,
        const float* __restrict__ S, float* __restrict__ P) {
    const int c = blockIdx.x + CSKIP;     // 2..19
    const int b = blockIdx.y;
    const int lane = threadIdx.x;
    const int h = lane * 4;

    const float AMIN = 0.81873075307798182f, AMAX = 0.96078943915232320f;
    float4 al = *(const float4*)(alpha + h);
    float a[4]  = {fminf(fmaxf(al.x, AMIN), AMAX), fminf(fmaxf(al.y, AMIN), AMAX),
                   fminf(fmaxf(al.z, AMIN), AMAX), fminf(fmaxf(al.w, AMIN), AMAX)};
    float om[4] = {1.f - a[0], 1.f - a[1], 1.f - a[2], 1.f - a[3]};

    float4 s0 = *(const float4*)(S + ((size_t)b * NCH + c) * H_ + h);
    float ut[4]   = {s0.x, s0.y, s0.z, s0.w};
    float acc4[4] = {0.f, 0.f, 0.f, 0.f};

    const unsigned short* base = Wx + ((size_t)b * T_ + c * CHUNK) * H_ + h;
#pragma unroll
    for (int tb = 0; tb < CHUNK; tb += 5) {
        float e[5][4], sl[5];
#pragma unroll
        for (int q = 0; q < 5; ++q) {
            ull wv = *(const ull*)(base + (size_t)(tb + q) * H_);
            ut[0] = a[0] * ut[0] + om[0] * bf2f((unsigned short)wv);
            ut[1] = a[1] * ut[1] + om[1] * bf2f((unsigned short)(wv >> 16));
            ut[2] = a[2] * ut[2] + om[2] * bf2f((unsigned short)(wv >> 32));
            ut[3] = a[3] * ut[3] + om[3] * bf2f((unsigned short)(wv >> 48));
            e[q][0] = __expf(ut[0]);   // |ut| small: overflow impossible
            e[q][1] = __expf(ut[1]);
            e[q][2] = __expf(ut[2]);
            e[q][3] = __expf(ut[3]);
            sl[q] = (e[q][0] + e[q][1]) + (e[q][2] + e[q][3]);
        }
#pragma unroll
        for (int dd = 1; dd < 64; dd <<= 1) {
            sl[0] += __shfl_xor(sl[0], dd);
            sl[1] += __shfl_xor(sl[1], dd);
            sl[2] += __shfl_xor(sl[2], dd);
            sl[3] += __shfl_xor(sl[3], dd);
            sl[4] += __shfl_xor(sl[4], dd);
        }
#pragma unroll
        for (int q = 0; q < 5; ++q) {
            const float rcp = 1.0f / sl[q];
            acc4[0] += e[q][0] * rcp;
            acc4[1] += e[q][1] * rcp;
            acc4[2] += e[q][2] * rcp;
            acc4[3] += e[q][3] * rcp;
        }
    }
    float4 o; o.x = acc4[0]; o.y = acc4[1]; o.z = acc4[2]; o.w = acc4[3];
    *(float4*)(P + ((size_t)b * NCH + c) * H_ + h) = o;
}

__global__ __launch_bounds__(256) void scanD_kernel(
        const float* __restrict__ P, float* __restrict__ out) {
    const int b = blockIdx.x, h = threadIdx.x;
    float s = 0.f;
    for (int c = CSKIP; c < NCH; ++c) s += P[((size_t)b * NCH + c) * H_ + h];
    out[(size_t)b * H_ + h] = s;
}

extern "C" void kernel_launch(void* const* d_in, const int* in_sizes, int n_in,
                              void* d_out, int out_size, void* d_ws, size_t ws_size,
                              hipStream_t stream) {
    const float* x     = (const float*)d_in[0];   // [B,T,D]
    const float* W     = (const float*)d_in[1];   // [H,D]
    const float* alpha = (const float*)d_in[2];   // [H]
    float* out = (float*)d_out;                   // [B,H]

    char* ws = (char*)d_ws;
    unsigned short* Wbf = (unsigned short*)ws;                        // 512 KB
    unsigned short* Wx  = (unsigned short*)(ws + ((size_t)1 << 20));  // 65.5 MB
    float* F = (float*)(ws + ((size_t)70 << 20));                     // 2.62 MB
    float* S = (float*)(ws + ((size_t)80 << 20));                     // 2.62 MB
    float* P = (float*)(ws + ((size_t)90 << 20));                     // 2.62 MB

    wconv_kernel<<<128, 256, 0, stream>>>(W, Wbf);
    gemm_kernel<<<(B_ * T_) / 128, 512, 0, stream>>>(x, Wbf, Wx);
    scanA_kernel<<<dim3(NCH, B_), 64, 0, stream>>>(Wx, alpha, F);
    scanB_kernel<<<B_, H_, 0, stream>>>(F, alpha, S);
    scanC_kernel<<<dim3(NCH - CSKIP, B_), 64, 0, stream>>>(Wx, alpha, S, P);
    scanD_kernel<<<B_, 256, 0, stream>>>(P, out);
}